// Round 10
// baseline (138.021 us; speedup 1.0000x reference)
//
#include <hip/hip_runtime.h>

constexpr int H = 4096;
constexpr int W = 4096;
constexpr int NPIX = H * W;           // 16,777,216
constexpr int W4   = W / 4;           // 1024 float4 per row
constexpr int NU8  = 2 * H;           // 8192 half-row units (2048 floats each)
constexpr int K1_BLOCKS = 2048;
constexpr int K1_UNITS  = NU8 / K1_BLOCKS;   // 4 units = 2 adjacent rows per block
constexpr int K2_BLOCKS = NU8;        // 8192 blocks, 1 half-row each

typedef float f32x4 __attribute__((ext_vector_type(4)));

__device__ __forceinline__ float dot4(f32x4 a, f32x4 b) {
    return a.x*b.x + a.y*b.y + a.z*b.z + a.w*b.w;
}

// ---- wave64 reduce of 4 values ----
__device__ __forceinline__ void waveRed4(float& a, float& b, float& c, float& d) {
    #pragma unroll
    for (int o = 32; o > 0; o >>= 1) {
        a += __shfl_down(a, o, 64);
        b += __shfl_down(b, o, 64);
        c += __shfl_down(c, o, 64);
        d += __shfl_down(d, o, 64);
    }
}

// 3-tap horizontal conv over 8 contiguous floats (A,B) with halo scalars l,r
__device__ __forceinline__ void conv8_row(f32x4 A, f32x4 B, float l, float r,
                                          float f0, float f1, float f2,
                                          f32x4& lo, f32x4& hi) {
    lo.x = f0*l   + f1*A.x + f2*A.y;
    lo.y = f0*A.x + f1*A.y + f2*A.z;
    lo.z = f0*A.y + f1*A.z + f2*A.w;
    lo.w = f0*A.z + f1*A.w + f2*B.x;
    hi.x = f0*A.w + f1*B.x + f2*B.y;
    hi.y = f0*B.x + f1*B.y + f2*B.z;
    hi.z = f0*B.y + f1*B.z + f2*B.w;
    hi.w = f0*B.z + f1*B.w + f2*r;
}

// conv(p) for 8 floats of half-row unit u; also returns center p values
__device__ __forceinline__ void conv_unit8(const float* __restrict__ p,
                                           const float f[9], int u, int lane,
                                           f32x4& cv_lo, f32x4& cv_hi,
                                           f32x4& pA, f32x4& pB) {
    const int h  = u >> 1;
    const int w8 = ((u & 1) << 8) + threadIdx.x;   // 0..511
    const int w4 = w8 << 1;
    const int w0 = w8 << 3;

    const float* __restrict__ rowc = p + (size_t)h * W;
    const float* __restrict__ rowm = p + (size_t)(h > 0     ? h - 1 : 0    ) * W;
    const float* __restrict__ rowp = p + (size_t)(h < H - 1 ? h + 1 : H - 1) * W;
    const float mM = (h > 0)     ? 1.f : 0.f;
    const float pM = (h < H - 1) ? 1.f : 0.f;

    const f32x4 Am = reinterpret_cast<const f32x4*>(rowm)[w4];
    const f32x4 Bm = reinterpret_cast<const f32x4*>(rowm)[w4 + 1];
    const f32x4 Ac = reinterpret_cast<const f32x4*>(rowc)[w4];
    const f32x4 Bc = reinterpret_cast<const f32x4*>(rowc)[w4 + 1];
    const f32x4 Ap = reinterpret_cast<const f32x4*>(rowp)[w4];
    const f32x4 Bp = reinterpret_cast<const f32x4*>(rowp)[w4 + 1];

    // halo scalars from neighbor lanes (they hold them in registers)
    float lm = __shfl_up(Bm.w, 1, 64);
    float lc = __shfl_up(Bc.w, 1, 64);
    float lp = __shfl_up(Bp.w, 1, 64);
    float rm = __shfl_down(Am.x, 1, 64);
    float rc = __shfl_down(Ac.x, 1, 64);
    float rp = __shfl_down(Ap.x, 1, 64);
    if (lane == 0) {           // wave-left boundary: exec-masked tiny loads
        lm = (w0 > 0) ? rowm[w0 - 1] : 0.f;
        lc = (w0 > 0) ? rowc[w0 - 1] : 0.f;
        lp = (w0 > 0) ? rowp[w0 - 1] : 0.f;
    }
    if (lane == 63) {          // wave-right boundary
        rm = (w0 + 8 < W) ? rowm[w0 + 8] : 0.f;
        rc = (w0 + 8 < W) ? rowc[w0 + 8] : 0.f;
        rp = (w0 + 8 < W) ? rowp[w0 + 8] : 0.f;
    }

    f32x4 lo, hi, tlo, thi;
    conv8_row(Ac, Bc, lc, rc, f[3], f[4], f[5], lo, hi);
    conv8_row(Am, Bm, lm, rm, f[0], f[1], f[2], tlo, thi);
    lo += tlo * mM;  hi += thi * mM;
    conv8_row(Ap, Bp, lp, rp, f[6], f[7], f[8], tlo, thi);
    lo += tlo * pM;  hi += thi * pM;

    cv_lo = lo; cv_hi = hi;
    pA = Ac;    pB = Bc;
}

// ---- K1: per-block partial sums over 4 half-row units (2 adjacent rows) ----
__global__ __launch_bounds__(256) void k1_sums(const float* __restrict__ r0,
                                               const float* __restrict__ p,
                                               const float* __restrict__ filt,
                                               float* __restrict__ partials) {
    __shared__ float sred[4][4];
    float f[9];
    #pragma unroll
    for (int i = 0; i < 9; ++i) f[i] = filt[i];

    const int lane = threadIdx.x & 63;
    const int wid  = threadIdx.x >> 6;

    float s0 = 0.f, s1 = 0.f, s2 = 0.f, s3 = 0.f;
    const int u0 = blockIdx.x * K1_UNITS;
    #pragma unroll 2
    for (int i = 0; i < K1_UNITS; ++i) {
        const int u  = u0 + i;
        const int h  = u >> 1;
        const int w4 = (((u & 1) << 8) + threadIdx.x) << 1;
        f32x4 cvl, cvh, pA, pB;
        conv_unit8(p, f, u, lane, cvl, cvh, pA, pB);
        const f32x4 rA = reinterpret_cast<const f32x4*>(r0 + (size_t)h * W)[w4];
        const f32x4 rB = reinterpret_cast<const f32x4*>(r0 + (size_t)h * W)[w4 + 1];
        s0 += dot4(rA, rA) + dot4(rB, rB);
        s1 += dot4(pA, cvl) + dot4(pB, cvh);
        s2 += dot4(rA, cvl) + dot4(rB, cvh);
        s3 += dot4(cvl, cvl) + dot4(cvh, cvh);
    }
    waveRed4(s0, s1, s2, s3);
    if (lane == 0) { sred[wid][0] = s0; sred[wid][1] = s1; sred[wid][2] = s2; sred[wid][3] = s3; }
    __syncthreads();
    if (threadIdx.x == 0) {
        f32x4 pv;
        pv.x = sred[0][0] + sred[1][0] + sred[2][0] + sred[3][0];
        pv.y = sred[0][1] + sred[1][1] + sred[2][1] + sred[3][1];
        pv.z = sred[0][2] + sred[1][2] + sred[2][2] + sred[3][2];
        pv.w = sred[0][3] + sred[1][3] + sred[2][3] + sred[3][3];
        reinterpret_cast<f32x4*>(partials)[blockIdx.x] = pv;
    }
}

// ---- K_reduce: fold 2048 partial-vectors, compute alpha, beta, r1_sum ----
__global__ __launch_bounds__(1024) void k_reduce(const float* __restrict__ partials,
                                                 float* __restrict__ scalars) {
    __shared__ float sred[16][4];
    const int lane = threadIdx.x & 63;
    const int wid  = threadIdx.x >> 6;

    f32x4 acc = reinterpret_cast<const f32x4*>(partials)[threadIdx.x]
              + reinterpret_cast<const f32x4*>(partials)[threadIdx.x + 1024];
    float s0 = acc.x, s1 = acc.y, s2 = acc.z, s3 = acc.w;
    waveRed4(s0, s1, s2, s3);
    if (lane == 0) { sred[wid][0] = s0; sred[wid][1] = s1; sred[wid][2] = s2; sred[wid][3] = s3; }
    __syncthreads();
    if (threadIdx.x == 0) {
        float rr0 = 0.f, pap = 0.f, r0c = 0.f, cc = 0.f;
        #pragma unroll
        for (int wv = 0; wv < 16; ++wv) {
            rr0 += sred[wv][0]; pap += sred[wv][1];
            r0c += sred[wv][2]; cc  += sred[wv][3];
        }
        const float alpha = rr0 / pap;
        const float r1s   = rr0 - 2.f * alpha * r0c + alpha * alpha * cc;
        scalars[0] = alpha;
        scalars[1] = r1s / rr0;   // beta
        scalars[2] = r1s;
    }
}

// ---- K2: fused update, one half-row (8 floats/thread) per block ----
__global__ __launch_bounds__(256) void k2_update(const float* __restrict__ r0,
                                                 const float* __restrict__ p,
                                                 const float* __restrict__ phi,
                                                 const float* __restrict__ filt,
                                                 const float* __restrict__ scalars,
                                                 float* __restrict__ out) {
    const float alpha = scalars[0];
    const float beta  = scalars[1];

    float f[9];
    #pragma unroll
    for (int i = 0; i < 9; ++i) f[i] = filt[i];

    const int lane = threadIdx.x & 63;
    const int u  = blockIdx.x;
    const int h  = u >> 1;
    const int w4 = (((u & 1) << 8) + threadIdx.x) << 1;
    const size_t vv = (size_t)h * W4 + w4;

    f32x4 cvl, cvh, pA, pB;
    conv_unit8(p, f, u, lane, cvl, cvh, pA, pB);
    const f32x4 rA = reinterpret_cast<const f32x4*>(r0 + (size_t)h * W)[w4];
    const f32x4 rB = reinterpret_cast<const f32x4*>(r0 + (size_t)h * W)[w4 + 1];
    const f32x4 phA = reinterpret_cast<const f32x4*>(phi)[vv];       // plain: L3-retain
    const f32x4 phB = reinterpret_cast<const f32x4*>(phi)[vv + 1];

    const f32x4 r1A = rA - alpha * cvl;
    const f32x4 r1B = rB - alpha * cvh;
    const f32x4 pnA = r1A + beta * pA;
    const f32x4 pnB = r1B + beta * pB;
    const f32x4 poA = phA + alpha * pA;
    const f32x4 poB = phB + alpha * pB;

    f32x4* __restrict__ r1_out  = reinterpret_cast<f32x4*>(out);
    f32x4* __restrict__ pn_out  = reinterpret_cast<f32x4*>(out + (size_t)NPIX);
    f32x4* __restrict__ phi_out = reinterpret_cast<f32x4*>(out + 2 * (size_t)NPIX);
    __builtin_nontemporal_store(r1A, r1_out  + vv);
    __builtin_nontemporal_store(r1B, r1_out  + vv + 1);
    __builtin_nontemporal_store(pnA, pn_out  + vv);
    __builtin_nontemporal_store(pnB, pn_out  + vv + 1);
    __builtin_nontemporal_store(poA, phi_out + vv);
    __builtin_nontemporal_store(poB, phi_out + vv + 1);

    if (u == 0 && threadIdx.x == 0) out[3 * (size_t)NPIX] = scalars[2];
}

extern "C" void kernel_launch(void* const* d_in, const int* in_sizes, int n_in,
                              void* d_out, int out_size, void* d_ws, size_t ws_size,
                              hipStream_t stream) {
    const float* r0   = (const float*)d_in[0];
    const float* p    = (const float*)d_in[1];
    const float* phi  = (const float*)d_in[2];
    const float* filt = (const float*)d_in[3];
    float* out      = (float*)d_out;
    float* partials = (float*)d_ws;                 // 4 * K1_BLOCKS floats
    float* scalars  = partials + 4 * K1_BLOCKS;     // alpha, beta, r1_sum

    hipLaunchKernelGGL(k1_sums,  dim3(K1_BLOCKS), dim3(256),  0, stream, r0, p, filt, partials);
    hipLaunchKernelGGL(k_reduce, dim3(1),         dim3(1024), 0, stream, partials, scalars);
    hipLaunchKernelGGL(k2_update,dim3(K2_BLOCKS), dim3(256),  0, stream, r0, p, phi, filt, scalars, out);
}

// Round 11
// 107.202 us; speedup vs baseline: 1.2875x; 1.2875x over previous
//
#include <hip/hip_runtime.h>

constexpr int H = 4096;
constexpr int W = 4096;
constexpr int NPIX = H * W;           // 16,777,216
constexpr int W4   = W / 4;           // 1024 float4 per row
constexpr int NUNIT = 4 * H;          // 16384 quarter-row units
constexpr int K1_BLOCKS = 2048;
constexpr int K1_UNITS  = NUNIT / K1_BLOCKS;   // 8 units (2 rows) per block
constexpr int K2_BLOCKS = NUNIT / 2;  // 8192 blocks, 2 units (same row) each

typedef float f32x4 __attribute__((ext_vector_type(4)));

// XCD-aware bijective swizzle: give each of the 8 XCDs a contiguous block chunk
// so stencil-sharing neighbor rows live in the same per-XCD L2.
__device__ __forceinline__ int xcd_swizzle(int b, int nper) {
    return (b & 7) * nper + (b >> 3);
}

// ---- wave64 reduce of 4 values ----
__device__ __forceinline__ void waveRed4(float& a, float& b, float& c, float& d) {
    #pragma unroll
    for (int o = 32; o > 0; o >>= 1) {
        a += __shfl_down(a, o, 64);
        b += __shfl_down(b, o, 64);
        c += __shfl_down(c, o, 64);
        d += __shfl_down(d, o, 64);
    }
}

// 3-tap horizontal conv for a float4 given left/right edge scalars
__device__ __forceinline__ float4 rowconv(float l, float4 c, float r, float f0, float f1, float f2) {
    float4 o;
    o.x = f0 * l   + f1 * c.x + f2 * c.y;
    o.y = f0 * c.x + f1 * c.y + f2 * c.z;
    o.z = f0 * c.y + f1 * c.z + f2 * c.w;
    o.w = f0 * c.z + f1 * c.w + f2 * r;
    return o;
}

// compute conv(p) float4 + center p float4 for unit u (quarter-row)
__device__ __forceinline__ void conv_unit(const float* __restrict__ p,
                                          const float f[9], int u,
                                          float4& cv_out, float4& pc_out) {
    const int h  = u >> 2;
    const int w4 = ((u & 3) << 8) + threadIdx.x;
    const int w0 = w4 << 2;

    const float* __restrict__ rowc = p + (size_t)h * W;
    const float* __restrict__ rowm = p + (size_t)(h > 0     ? h - 1 : 0    ) * W;
    const float* __restrict__ rowp = p + (size_t)(h < H - 1 ? h + 1 : H - 1) * W;
    const float mM = (h > 0)     ? 1.f : 0.f;
    const float pM = (h < H - 1) ? 1.f : 0.f;

    const float4 cm  = reinterpret_cast<const float4*>(rowm)[w4];
    const float4 cc4 = reinterpret_cast<const float4*>(rowc)[w4];
    const float4 cp  = reinterpret_cast<const float4*>(rowp)[w4];
    const int li = (w0 > 0) ? w0 - 1 : 0;
    const int ri = (w0 + 4 < W) ? w0 + 4 : W - 1;
    float lm = rowm[li], lc = rowc[li], lp = rowp[li];
    float rm = rowm[ri], rc = rowc[ri], rp = rowp[ri];

    const float lM = (w0 > 0) ? 1.f : 0.f;
    const float rM = (w0 + 4 < W) ? 1.f : 0.f;
    lm *= lM; lc *= lM; lp *= lM;
    rm *= rM; rc *= rM; rp *= rM;

    float4 cv = rowconv(lc, cc4, rc, f[3], f[4], f[5]);
    const float4 tm = rowconv(lm, cm, rm, f[0], f[1], f[2]);
    const float4 tp = rowconv(lp, cp, rp, f[6], f[7], f[8]);
    cv.x = fmaf(mM, tm.x, fmaf(pM, tp.x, cv.x));
    cv.y = fmaf(mM, tm.y, fmaf(pM, tp.y, cv.y));
    cv.z = fmaf(mM, tm.z, fmaf(pM, tp.z, cv.z));
    cv.w = fmaf(mM, tm.w, fmaf(pM, tp.w, cv.w));

    cv_out = cv;
    pc_out = cc4;
}

// ---- K1: per-block partial sums over 8 units (2 adjacent rows) ----
__global__ __launch_bounds__(256) void k1_sums(const float* __restrict__ r0,
                                               const float* __restrict__ p,
                                               const float* __restrict__ filt,
                                               float* __restrict__ partials) {
    __shared__ float sred[4][4];
    float f[9];
    #pragma unroll
    for (int i = 0; i < 9; ++i) f[i] = filt[i];

    const int lane = threadIdx.x & 63;
    const int wid  = threadIdx.x >> 6;
    const int sb   = xcd_swizzle(blockIdx.x, K1_BLOCKS / 8);

    float s0 = 0.f, s1 = 0.f, s2 = 0.f, s3 = 0.f;
    const int u0 = sb * K1_UNITS;
    #pragma unroll 4
    for (int i = 0; i < K1_UNITS; ++i) {
        const int u = u0 + i;
        const int h  = u >> 2;
        const int w4 = ((u & 3) << 8) + threadIdx.x;
        float4 cv, pc;
        conv_unit(p, f, u, cv, pc);
        const float4 rv = reinterpret_cast<const float4*>(r0 + (size_t)h * W)[w4];
        s0 += rv.x*rv.x + rv.y*rv.y + rv.z*rv.z + rv.w*rv.w;
        s1 += pc.x*cv.x + pc.y*cv.y + pc.z*cv.z + pc.w*cv.w;
        s2 += rv.x*cv.x + rv.y*cv.y + rv.z*cv.z + rv.w*cv.w;
        s3 += cv.x*cv.x + cv.y*cv.y + cv.z*cv.z + cv.w*cv.w;
    }
    waveRed4(s0, s1, s2, s3);
    if (lane == 0) { sred[wid][0] = s0; sred[wid][1] = s1; sred[wid][2] = s2; sred[wid][3] = s3; }
    __syncthreads();
    if (threadIdx.x == 0) {
        f32x4 pv;
        pv.x = sred[0][0] + sred[1][0] + sred[2][0] + sred[3][0];
        pv.y = sred[0][1] + sred[1][1] + sred[2][1] + sred[3][1];
        pv.z = sred[0][2] + sred[1][2] + sred[2][2] + sred[3][2];
        pv.w = sred[0][3] + sred[1][3] + sred[2][3] + sred[3][3];
        reinterpret_cast<f32x4*>(partials)[blockIdx.x] = pv;
    }
}

// ---- K_reduce: fold 2048 partial-vectors, compute alpha, beta, r1_sum ----
__global__ __launch_bounds__(1024) void k_reduce(const float* __restrict__ partials,
                                                 float* __restrict__ scalars) {
    __shared__ float sred[16][4];
    const int lane = threadIdx.x & 63;
    const int wid  = threadIdx.x >> 6;

    f32x4 acc = reinterpret_cast<const f32x4*>(partials)[threadIdx.x]
              + reinterpret_cast<const f32x4*>(partials)[threadIdx.x + 1024];
    float s0 = acc.x, s1 = acc.y, s2 = acc.z, s3 = acc.w;
    waveRed4(s0, s1, s2, s3);
    if (lane == 0) { sred[wid][0] = s0; sred[wid][1] = s1; sred[wid][2] = s2; sred[wid][3] = s3; }
    __syncthreads();
    if (threadIdx.x == 0) {
        float rr0 = 0.f, pap = 0.f, r0c = 0.f, cc = 0.f;
        #pragma unroll
        for (int wv = 0; wv < 16; ++wv) {
            rr0 += sred[wv][0]; pap += sred[wv][1];
            r0c += sred[wv][2]; cc  += sred[wv][3];
        }
        const float alpha = rr0 / pap;
        const float r1s   = rr0 - 2.f * alpha * r0c + alpha * alpha * cc;
        scalars[0] = alpha;
        scalars[1] = r1s / rr0;   // beta
        scalars[2] = r1s;
    }
}

// ---- K2: r1 = r0 - alpha*c; p_new = r1 + beta*p; phi_new = phi + alpha*p ----
// 2 quarter-row units per block (same row); XCD-swizzled row chunks
__global__ __launch_bounds__(256) void k2_update(const float* __restrict__ r0,
                                                 const float* __restrict__ p,
                                                 const float* __restrict__ phi,
                                                 const float* __restrict__ filt,
                                                 const float* __restrict__ scalars,
                                                 float* __restrict__ out) {
    const float alpha = scalars[0];
    const float beta  = scalars[1];

    float f[9];
    #pragma unroll
    for (int i = 0; i < 9; ++i) f[i] = filt[i];

    const int sb = xcd_swizzle(blockIdx.x, K2_BLOCKS / 8);

    f32x4* __restrict__ r1_out  = reinterpret_cast<f32x4*>(out);
    f32x4* __restrict__ pn_out  = reinterpret_cast<f32x4*>(out + (size_t)NPIX);
    f32x4* __restrict__ phi_out = reinterpret_cast<f32x4*>(out + 2 * (size_t)NPIX);

    #pragma unroll
    for (int k = 0; k < 2; ++k) {
        const int u = sb * 2 + k;
        const int h  = u >> 2;
        const int w4 = ((u & 3) << 8) + threadIdx.x;
        const size_t vv = (size_t)h * W4 + w4;

        float4 cv, pc;
        conv_unit(p, f, u, cv, pc);
        const float4 rv = reinterpret_cast<const float4*>(r0 + (size_t)h * W)[w4];
        const f32x4 ph = reinterpret_cast<const f32x4*>(phi)[vv];   // plain load: L3-retain phi

        f32x4 r1;
        r1.x = fmaf(-alpha, cv.x, rv.x);
        r1.y = fmaf(-alpha, cv.y, rv.y);
        r1.z = fmaf(-alpha, cv.z, rv.z);
        r1.w = fmaf(-alpha, cv.w, rv.w);
        f32x4 pn;
        pn.x = fmaf(beta, pc.x, r1.x);
        pn.y = fmaf(beta, pc.y, r1.y);
        pn.z = fmaf(beta, pc.z, r1.z);
        pn.w = fmaf(beta, pc.w, r1.w);
        f32x4 pho;
        pho.x = fmaf(alpha, pc.x, ph.x);
        pho.y = fmaf(alpha, pc.y, ph.y);
        pho.z = fmaf(alpha, pc.z, ph.z);
        pho.w = fmaf(alpha, pc.w, ph.w);

        __builtin_nontemporal_store(r1,  r1_out  + vv);
        __builtin_nontemporal_store(pn,  pn_out  + vv);
        __builtin_nontemporal_store(pho, phi_out + vv);
    }
    if (blockIdx.x == 0 && threadIdx.x == 0) out[3 * (size_t)NPIX] = scalars[2];
}

extern "C" void kernel_launch(void* const* d_in, const int* in_sizes, int n_in,
                              void* d_out, int out_size, void* d_ws, size_t ws_size,
                              hipStream_t stream) {
    const float* r0   = (const float*)d_in[0];
    const float* p    = (const float*)d_in[1];
    const float* phi  = (const float*)d_in[2];
    const float* filt = (const float*)d_in[3];
    float* out      = (float*)d_out;
    float* partials = (float*)d_ws;                 // 4 * K1_BLOCKS floats
    float* scalars  = partials + 4 * K1_BLOCKS;     // alpha, beta, r1_sum

    hipLaunchKernelGGL(k1_sums,  dim3(K1_BLOCKS), dim3(256),  0, stream, r0, p, filt, partials);
    hipLaunchKernelGGL(k_reduce, dim3(1),         dim3(1024), 0, stream, partials, scalars);
    hipLaunchKernelGGL(k2_update,dim3(K2_BLOCKS), dim3(256),  0, stream, r0, p, phi, filt, scalars, out);
}